// Round 1
// baseline (2290.526 us; speedup 1.0000x reference)
//
#include <hip/hip_runtime.h>
#include <hip/hip_bf16.h>
#include <stdint.h>

// Problem constants
#define BATCH_ 256
#define SEQ_   128
#define DIN_   768
#define HID_   512
#define NG_    2048   // 4*HID
#define NCLS_  9

typedef unsigned short u16;
typedef __attribute__((ext_vector_type(8))) short bf16x8;
typedef __attribute__((ext_vector_type(4))) float f32x4;

__device__ __forceinline__ float bf2f(u16 u) {
  return __builtin_bit_cast(float, (uint32_t)u << 16);
}
__device__ __forceinline__ u16 f2bf(float f) {
  uint32_t x = __builtin_bit_cast(uint32_t, f);
  uint32_t r = (x + 0x7fffu + ((x >> 16) & 1u)) >> 16;  // RNE
  return (u16)r;
}

// async global->LDS, 16B per lane. LDS dest must be linear in lane order.
__device__ __forceinline__ void gload_lds16(const void* g, void* l) {
#if defined(__has_builtin)
#if __has_builtin(__builtin_amdgcn_global_load_lds)
  __builtin_amdgcn_global_load_lds((const __attribute__((address_space(1))) void*)g,
                                   (__attribute__((address_space(3))) void*)l, 16, 0, 0);
  return;
#endif
#endif
  *(uint4*)l = *(const uint4*)g;  // fallback (sync copy through regs)
}

// ---------------- f32 -> bf16 cast (weights) ----------------
__global__ void castk(const float* __restrict__ s, u16* __restrict__ d, int n4) {
  int i = blockIdx.x * blockDim.x + threadIdx.x;
  if (i < n4) {
    float4 v = ((const float4*)s)[i];
    ushort4 o;
    o.x = f2bf(v.x); o.y = f2bf(v.y); o.z = f2bf(v.z); o.w = f2bf(v.w);
    ((ushort4*)d)[i] = o;
  }
}

// ---------------- embed gather + add pos + cast, (S,B,768) bf16 ----------------
__global__ __launch_bounds__(192) void embed_k(const int* __restrict__ ids,
                                               const float* __restrict__ tok,
                                               const float* __restrict__ pos,
                                               u16* __restrict__ X) {
  const int row = blockIdx.x;          // row = t*256 + b
  const int t = row >> 8, b = row & 255;
  const int id = ids[b * SEQ_ + t];    // input_ids is (B,S)
  const float4* tr = (const float4*)(tok + (size_t)id * DIN_);
  const float4* pr = (const float4*)(pos + (size_t)t * DIN_);
  const int i = threadIdx.x;           // 192 threads * 4 floats = 768
  float4 v = tr[i], p = pr[i];
  ushort4 o;
  o.x = f2bf(v.x + p.x); o.y = f2bf(v.y + p.y);
  o.z = f2bf(v.z + p.z); o.w = f2bf(v.w + p.w);
  ((ushort4*)(X + (size_t)row * DIN_))[i] = o;
}

// ---------------- bf16 GEMM, C[m][n] = sum_k A[m][k]*B[n][k] + bias[n] ----------------
// 128x128 tile, BK=64, 4 waves (2x2 of 64x64), 16x16x32 MFMA (m97 structure).
__global__ __launch_bounds__(256) void gemm_bt(const u16* __restrict__ A,
                                               const u16* __restrict__ Bm,
                                               const float* __restrict__ bias,
                                               u16* __restrict__ C,
                                               int M, int N, int K) {
  __shared__ __align__(16) u16 As[128 * 64];
  __shared__ __align__(16) u16 Bs[128 * 64];
  const int tid = threadIdx.x;
  const int lane = tid & 63;
  const int wave = tid >> 6;
  const int m0 = blockIdx.y * 128;
  const int n0 = blockIdx.x * 128;
  const int wm = (wave >> 1) * 64;
  const int wn = (wave & 1) * 64;
  const int lr = lane & 15;
  const int lg = lane >> 4;
  f32x4 acc[4][4] = {};

  for (int k0 = 0; k0 < K; k0 += 64) {
#pragma unroll
    for (int it = 0; it < 4; ++it) {
      int e = it * 256 + tid;
      int r = e >> 3, c8 = (e & 7) * 8;
      gload_lds16(A + (size_t)(m0 + r) * K + k0 + c8, &As[e * 8]);
      gload_lds16(Bm + (size_t)(n0 + r) * K + k0 + c8, &Bs[e * 8]);
    }
    __syncthreads();
#pragma unroll
    for (int kk = 0; kk < 64; kk += 32) {
      bf16x8 af[4], bfr[4];
#pragma unroll
      for (int i = 0; i < 4; ++i) {
        af[i]  = *(const bf16x8*)&As[(wm + i * 16 + lr) * 64 + kk + lg * 8];
        bfr[i] = *(const bf16x8*)&Bs[(wn + i * 16 + lr) * 64 + kk + lg * 8];
      }
#pragma unroll
      for (int i = 0; i < 4; ++i)
#pragma unroll
        for (int j = 0; j < 4; ++j)
          acc[i][j] = __builtin_amdgcn_mfma_f32_16x16x32_bf16(af[i], bfr[j], acc[i][j], 0, 0, 0);
    }
    __syncthreads();
  }
  // epilogue: C/D layout col=lane&15, row=(lane>>4)*4+q  [m89-verified]
#pragma unroll
  for (int i = 0; i < 4; ++i) {
#pragma unroll
    for (int j = 0; j < 4; ++j) {
      int col = n0 + wn + j * 16 + lr;
      float bv = bias[col];
#pragma unroll
      for (int q = 0; q < 4; ++q) {
        int row = m0 + wm + i * 16 + lg * 4 + q;
        C[(size_t)row * N + col] = f2bf(acc[i][j][q] + bv);
      }
    }
  }
}

// ---------------- fused per-step LSTM cell kernel ----------------
// Block computes 32 batch rows x 16 hidden cols, all 4 gates (one gate per wave).
// G = Xpre (has x@W + b) + Hprev@R^T; then gates + cell update.
__global__ __launch_bounds__(256) void lstm_gate(const u16* __restrict__ Xpre,  // (256,2048) bf16
                                                 const u16* __restrict__ Hprev, // (256,512)  bf16
                                                 const u16* __restrict__ R,     // (2048,512) bf16
                                                 float* __restrict__ c,         // (256,512)  f32
                                                 u16* __restrict__ Hout) {      // (256,512)  bf16
  __shared__ __align__(16) u16 As[32 * 64];
  __shared__ __align__(16) u16 Bs[64 * 64];   // 4 gates x 16 rows x 64 k
  __shared__ float Gs[4][32][16];
  const int tid = threadIdx.x;
  const int lane = tid & 63;
  const int w = tid >> 6;                 // wave == gate index
  const int m0 = blockIdx.x * 32;
  const int j0 = blockIdx.y * 16;
  const int lr = lane & 15, lg = lane >> 4;
  f32x4 acc[2] = {};

  for (int k0 = 0; k0 < HID_; k0 += 64) {
    {
      int r = tid >> 3, c8 = (tid & 7) * 8;
      gload_lds16(Hprev + (size_t)(m0 + r) * HID_ + k0 + c8, &As[tid * 8]);
#pragma unroll
      for (int it = 0; it < 2; ++it) {
        int e = it * 256 + tid;
        int rr = e >> 3, cc = (e & 7) * 8;   // rr 0..63: gate=rr>>4, jj=rr&15
        int g = rr >> 4, jj = rr & 15;
        gload_lds16(R + (size_t)(g * HID_ + j0 + jj) * HID_ + k0 + cc, &Bs[e * 8]);
      }
    }
    __syncthreads();
#pragma unroll
    for (int kk = 0; kk < 64; kk += 32) {
      bf16x8 b  = *(const bf16x8*)&Bs[(w * 16 + lr) * 64 + kk + lg * 8];
      bf16x8 a0 = *(const bf16x8*)&As[(lr) * 64 + kk + lg * 8];
      bf16x8 a1 = *(const bf16x8*)&As[(16 + lr) * 64 + kk + lg * 8];
      acc[0] = __builtin_amdgcn_mfma_f32_16x16x32_bf16(a0, b, acc[0], 0, 0, 0);
      acc[1] = __builtin_amdgcn_mfma_f32_16x16x32_bf16(a1, b, acc[1], 0, 0, 0);
    }
    __syncthreads();
  }
  // add Xpre (x@W + b part) and publish this wave's gate to LDS
#pragma unroll
  for (int mi = 0; mi < 2; ++mi) {
#pragma unroll
    for (int q = 0; q < 4; ++q) {
      int row = mi * 16 + lg * 4 + q;
      float v = acc[mi][q] + bf2f(Xpre[(size_t)(m0 + row) * NG_ + w * HID_ + j0 + lr]);
      Gs[w][row][lr] = v;
    }
  }
  __syncthreads();
  // elementwise cell update: 512 cells / 256 threads
  for (int cell = tid; cell < 512; cell += 256) {
    int bl = cell >> 4, jl = cell & 15;
    float gi = Gs[0][bl][jl], gf = Gs[1][bl][jl], gm = Gs[2][bl][jl], go = Gs[3][bl][jl];
    float iv = 1.f / (1.f + expf(-gi));
    float fv = 1.f / (1.f + expf(-gf));
    float mv = tanhf(gm);
    float ov = 1.f / (1.f + expf(-go));
    int idx = (m0 + bl) * HID_ + j0 + jl;
    float cn = mv * iv + fv * c[idx];
    c[idx] = cn;
    Hout[idx] = f2bf(ov * tanhf(cn));
  }
}

// ---------------- output projection: out[b][t][cls] = h2 . Wo[cls] + bo[cls] ----------------
__global__ __launch_bounds__(320) void out_proj(const u16* __restrict__ H2,   // (S*B,512) bf16
                                                const float* __restrict__ Wo, // (9,512)
                                                const float* __restrict__ bo,
                                                float* __restrict__ out) {    // (B,S,9)
  __shared__ __align__(16) u16 Hs[32 * 520];  // +8 pad kills bank conflicts
  const int r0 = blockIdx.x * 32;
  const int tid = threadIdx.x;
  for (int e = tid; e < 2048; e += 320) {
    int rl = e >> 6, k8 = (e & 63) * 8;
    *(uint4*)&Hs[rl * 520 + k8] = *(const uint4*)(H2 + (size_t)(r0 + rl) * HID_ + k8);
  }
  __syncthreads();
  if (tid < 288) {
    int rl = tid / 9, cls = tid - rl * 9;
    const u16* h = &Hs[rl * 520];
    const float* wv = Wo + cls * HID_;
    float s = bo[cls];
#pragma unroll 8
    for (int k = 0; k < HID_; ++k) s += bf2f(h[k]) * wv[k];
    int r = r0 + rl, t = r >> 8, b = r & 255;
    out[((size_t)b * SEQ_ + t) * NCLS_ + cls] = s;
  }
}

extern "C" void kernel_launch(void* const* d_in, const int* in_sizes, int n_in,
                              void* d_out, int out_size, void* d_ws, size_t ws_size,
                              hipStream_t stream) {
  (void)in_sizes; (void)n_in; (void)out_size; (void)ws_size;
  const int*   ids = (const int*)d_in[0];
  const float* tok = (const float*)d_in[1];
  const float* pos = (const float*)d_in[2];
  const float* W1  = (const float*)d_in[3];
  const float* R1  = (const float*)d_in[4];
  const float* b1  = (const float*)d_in[5];
  const float* W2  = (const float*)d_in[6];
  const float* R2  = (const float*)d_in[7];
  const float* b2  = (const float*)d_in[8];
  const float* Wo  = (const float*)d_in[9];
  const float* bo  = (const float*)d_in[10];
  float* out = (float*)d_out;

  // workspace layout (~229 MB); H2 overlays Xbf (dead after phase A)
  char* p = (char*)d_ws;
  auto alloc = [&](size_t bytes) { char* q = p; p += (bytes + 255) & ~(size_t)255; return q; };
  u16*  W1b = (u16*)alloc((size_t)NG_ * DIN_ * 2);
  u16*  R1b = (u16*)alloc((size_t)NG_ * HID_ * 2);
  u16*  W2b = (u16*)alloc((size_t)NG_ * HID_ * 2);
  u16*  R2b = (u16*)alloc((size_t)NG_ * HID_ * 2);
  float* c1 = (float*)alloc((size_t)BATCH_ * HID_ * 4);
  float* c2 = (float*)alloc((size_t)BATCH_ * HID_ * 4);
  u16*  hz  = (u16*)alloc((size_t)BATCH_ * HID_ * 2);
  u16*  Xbf = (u16*)alloc((size_t)SEQ_ * BATCH_ * DIN_ * 2);   // (S,B,768)
  u16*  Xpre= (u16*)alloc((size_t)SEQ_ * BATCH_ * NG_ * 2);    // (S,B,2048), reused layer2
  u16*  H1  = (u16*)alloc((size_t)SEQ_ * BATCH_ * HID_ * 2);   // (S,B,512)
  u16*  H2  = Xbf;  // overlay: Xbf dead after phase A

  // zero c1, c2, hz (contiguous, sizes are 256-multiples)
  hipMemsetAsync(c1, 0, (size_t)BATCH_ * HID_ * 4 * 2 + (size_t)BATCH_ * HID_ * 2, stream);

  // weight casts
  castk<<<dim3((NG_ * DIN_ / 4 + 255) / 256), 256, 0, stream>>>(W1, W1b, NG_ * DIN_ / 4);
  castk<<<dim3((NG_ * HID_ / 4 + 255) / 256), 256, 0, stream>>>(R1, R1b, NG_ * HID_ / 4);
  castk<<<dim3((NG_ * HID_ / 4 + 255) / 256), 256, 0, stream>>>(W2, W2b, NG_ * HID_ / 4);
  castk<<<dim3((NG_ * HID_ / 4 + 255) / 256), 256, 0, stream>>>(R2, R2b, NG_ * HID_ / 4);

  // embeds -> (S,B,768) bf16
  embed_k<<<dim3(SEQ_ * BATCH_), 192, 0, stream>>>(ids, tok, pos, Xbf);

  // phase A: X1pre = X @ W1^T + b1   (32768 x 2048, K=768)
  gemm_bt<<<dim3(NG_ / 128, SEQ_ * BATCH_ / 128), 256, 0, stream>>>(
      Xbf, W1b, b1, Xpre, SEQ_ * BATCH_, NG_, DIN_);

  // phase B: layer-1 recurrence
  for (int t = 0; t < SEQ_; ++t) {
    const u16* hp = t ? H1 + (size_t)(t - 1) * BATCH_ * HID_ : hz;
    lstm_gate<<<dim3(BATCH_ / 32, HID_ / 16), 256, 0, stream>>>(
        Xpre + (size_t)t * BATCH_ * NG_, hp, R1b, c1, H1 + (size_t)t * BATCH_ * HID_);
  }

  // phase C: X2pre = H1 @ W2^T + b2  (32768 x 2048, K=512)
  gemm_bt<<<dim3(NG_ / 128, SEQ_ * BATCH_ / 128), 256, 0, stream>>>(
      H1, W2b, b2, Xpre, SEQ_ * BATCH_, NG_, HID_);

  // phase D: layer-2 recurrence
  for (int t = 0; t < SEQ_; ++t) {
    const u16* hp = t ? H2 + (size_t)(t - 1) * BATCH_ * HID_ : hz;
    lstm_gate<<<dim3(BATCH_ / 32, HID_ / 16), 256, 0, stream>>>(
        Xpre + (size_t)t * BATCH_ * NG_, hp, R2b, c2, H2 + (size_t)t * BATCH_ * HID_);
  }

  // phase E: logits
  out_proj<<<dim3(SEQ_ * BATCH_ / 32), 320, 0, stream>>>(H2, Wo, bo, out);
}

// Round 2
// 1487.865 us; speedup vs baseline: 1.5395x; 1.5395x over previous
//
#include <hip/hip_runtime.h>
#include <hip/hip_bf16.h>
#include <stdint.h>

// Problem constants
#define BATCH_ 256
#define SEQ_   128
#define DIN_   768
#define HID_   512
#define NG_    2048   // 4*HID
#define NCLS_  9

typedef unsigned short u16;
typedef __attribute__((ext_vector_type(8))) short bf16x8;
typedef __attribute__((ext_vector_type(4))) float f32x4;

__device__ __forceinline__ float bf2f(u16 u) {
  return __builtin_bit_cast(float, (uint32_t)u << 16);
}
__device__ __forceinline__ u16 f2bf(float f) {
  uint32_t x = __builtin_bit_cast(uint32_t, f);
  uint32_t r = (x + 0x7fffu + ((x >> 16) & 1u)) >> 16;  // RNE
  return (u16)r;
}

// async global->LDS, 16B per lane. LDS dest must be linear in lane order.
__device__ __forceinline__ void gload_lds16(const void* g, void* l) {
#if defined(__has_builtin)
#if __has_builtin(__builtin_amdgcn_global_load_lds)
  __builtin_amdgcn_global_load_lds((const __attribute__((address_space(1))) void*)g,
                                   (__attribute__((address_space(3))) void*)l, 16, 0, 0);
  return;
#endif
#endif
  *(uint4*)l = *(const uint4*)g;  // fallback (sync copy through regs)
}

// ---------------- f32 -> bf16 cast (weights) ----------------
__global__ void castk(const float* __restrict__ s, u16* __restrict__ d, int n4) {
  int i = blockIdx.x * blockDim.x + threadIdx.x;
  if (i < n4) {
    float4 v = ((const float4*)s)[i];
    ushort4 o;
    o.x = f2bf(v.x); o.y = f2bf(v.y); o.z = f2bf(v.z); o.w = f2bf(v.w);
    ((ushort4*)d)[i] = o;
  }
}

// cast into packed [W2|R2] rows: src (2048,512) f32 -> dst rows stride 1024, col offset dstOff
__global__ void cast2(const float* __restrict__ s, u16* __restrict__ d, int dstOff) {
  int i = blockIdx.x * blockDim.x + threadIdx.x;  // f32x4 chunks, 2048*128 total
  if (i < 2048 * 128) {
    int row = i >> 7, c4 = i & 127;
    float4 v = ((const float4*)s)[i];
    ushort4 o;
    o.x = f2bf(v.x); o.y = f2bf(v.y); o.z = f2bf(v.z); o.w = f2bf(v.w);
    ((ushort4*)(d + (size_t)row * 1024 + dstOff))[c4] = o;
  }
}

// ---------------- embed gather + add pos + cast, (S,B,768) bf16 ----------------
__global__ __launch_bounds__(192) void embed_k(const int* __restrict__ ids,
                                               const float* __restrict__ tok,
                                               const float* __restrict__ pos,
                                               u16* __restrict__ X) {
  const int row = blockIdx.x;          // row = t*256 + b
  const int t = row >> 8, b = row & 255;
  const int id = ids[b * SEQ_ + t];    // input_ids is (B,S)
  const float4* tr = (const float4*)(tok + (size_t)id * DIN_);
  const float4* pr = (const float4*)(pos + (size_t)t * DIN_);
  const int i = threadIdx.x;           // 192 threads * 4 floats = 768
  float4 v = tr[i], p = pr[i];
  ushort4 o;
  o.x = f2bf(v.x + p.x); o.y = f2bf(v.y + p.y);
  o.z = f2bf(v.z + p.z); o.w = f2bf(v.w + p.w);
  ((ushort4*)(X + (size_t)row * DIN_))[i] = o;
}

// ---------------- bf16 GEMM, C[m][n] = sum_k A[m][k]*B[n][k] + bias[n] ----------------
// 128x128 tile, BK=64, 4 waves (2x2 of 64x64), 16x16x32 MFMA (m97 structure).
__global__ __launch_bounds__(256) void gemm_bt(const u16* __restrict__ A,
                                               const u16* __restrict__ Bm,
                                               const float* __restrict__ bias,
                                               u16* __restrict__ C,
                                               int M, int N, int K) {
  __shared__ __align__(16) u16 As[128 * 64];
  __shared__ __align__(16) u16 Bs[128 * 64];
  const int tid = threadIdx.x;
  const int lane = tid & 63;
  const int wave = tid >> 6;
  const int m0 = blockIdx.y * 128;
  const int n0 = blockIdx.x * 128;
  const int wm = (wave >> 1) * 64;
  const int wn = (wave & 1) * 64;
  const int lr = lane & 15;
  const int lg = lane >> 4;
  f32x4 acc[4][4] = {};

  for (int k0 = 0; k0 < K; k0 += 64) {
#pragma unroll
    for (int it = 0; it < 4; ++it) {
      int e = it * 256 + tid;
      int r = e >> 3, c8 = (e & 7) * 8;
      gload_lds16(A + (size_t)(m0 + r) * K + k0 + c8, &As[e * 8]);
      gload_lds16(Bm + (size_t)(n0 + r) * K + k0 + c8, &Bs[e * 8]);
    }
    __syncthreads();
#pragma unroll
    for (int kk = 0; kk < 64; kk += 32) {
      bf16x8 af[4], bfr[4];
#pragma unroll
      for (int i = 0; i < 4; ++i) {
        af[i]  = *(const bf16x8*)&As[(wm + i * 16 + lr) * 64 + kk + lg * 8];
        bfr[i] = *(const bf16x8*)&Bs[(wn + i * 16 + lr) * 64 + kk + lg * 8];
      }
#pragma unroll
      for (int i = 0; i < 4; ++i)
#pragma unroll
        for (int j = 0; j < 4; ++j)
          acc[i][j] = __builtin_amdgcn_mfma_f32_16x16x32_bf16(af[i], bfr[j], acc[i][j], 0, 0, 0);
    }
    __syncthreads();
  }
  // epilogue: C/D layout col=lane&15, row=(lane>>4)*4+q  [m89-verified]
#pragma unroll
  for (int i = 0; i < 4; ++i) {
#pragma unroll
    for (int j = 0; j < 4; ++j) {
      int col = n0 + wn + j * 16 + lr;
      float bv = bias[col];
#pragma unroll
      for (int q = 0; q < 4; ++q) {
        int row = m0 + wm + i * 16 + lg * 4 + q;
        C[(size_t)row * N + col] = f2bf(acc[i][j][q] + bv);
      }
    }
  }
}

// ---------------- fused wavefront step kernel ----------------
// Launch k: blocks [0,nL1) do layer1 step t=k; blocks [nL1,..) do layer2 step t=k-1.
// Acat slot layout: SLOT(t) row b = [ h1(t) (512) | h2(t-1) (512) ], row stride 1024.
// L1: G = Xpre_t + h1(t-1) @ R1^T            (K=512,  A = SLOT(k-1)[:,0:512])
// L2: G = b2 + [h1(t)|h2(t-1)] @ [W2|R2]^T   (K=1024, A = SLOT(k-1)[:,0:1024])
// Tile: 64 batch rows x 16 hid cols x 4 gates, 8 waves (one gate per wave pair).
// LDS slabs staged whole-K-pass with ONE barrier; T2 XOR swizzle (chunk ^= row&7)
// applied via pre-swizzled GLOBAL source addresses (gload_lds dest must be linear).
__global__ __launch_bounds__(512, 1) void lstm_step(
    const u16* __restrict__ Aprev,   // SLOT(k-1), (256,1024)
    u16* __restrict__ Aout,          // SLOT(k)
    const u16* __restrict__ Xpre,    // (256,2048) for L1
    const u16* __restrict__ R1b,     // (2048,512)
    const u16* __restrict__ W2cat,   // (2048,1024) = [W2|R2]
    const float* __restrict__ b2,    // (2048,)
    float* __restrict__ c1,
    float* __restrict__ c2,
    int nL1) {
  __shared__ __align__(16) u16 As[64 * 512];
  __shared__ __align__(16) u16 Bs[64 * 512];
  __shared__ float Gs[4][64][17];   // +1 pad: conflict-free f32 scatter
  const int tid = threadIdx.x;
  const int lane = tid & 63;
  const int w = tid >> 6;           // 0..7
  int bid = blockIdx.x;
  const bool isL2 = bid >= nL1;
  if (isL2) bid -= nL1;
  const int m0 = (bid & 3) * 64;    // batch tile
  const int j0 = (bid >> 2) * 16;   // hid-col tile
  const int npass = isL2 ? 2 : 1;
  const int bstride = isL2 ? 1024 : 512;
  const u16* Bmat = isL2 ? W2cat : R1b;

  const int g = w >> 1;             // gate of this wave
  const int mh = (w & 1) * 32;      // row half within 64
  const int lr = lane & 15, lg = lane >> 4;
  f32x4 acc[2] = {};

  for (int pass = 0; pass < npass; ++pass) {
    const int kbase = pass * 512;
    // stage As: 64 rows x 512 cols (64KB). One row per wave-iteration.
    // LDS[r][c] = G[r][c ^ (r&7)]  (c = 16B chunk index 0..63)
#pragma unroll
    for (int it = 0; it < 8; ++it) {
      int e = it * 512 + tid;
      int r = e >> 6;
      int csrc = (e & 63) ^ (r & 7);
      gload_lds16(Aprev + (size_t)(m0 + r) * 1024 + kbase + csrc * 8, &As[e * 8]);
    }
    // stage Bs: rows = gate*16 + jj (4 gates x 16 cols), same swizzle
#pragma unroll
    for (int it = 0; it < 8; ++it) {
      int e = it * 512 + tid;
      int r = e >> 6;
      int csrc = (e & 63) ^ (r & 7);
      int gg = r >> 4, jj = r & 15;
      gload_lds16(Bmat + (size_t)(gg * 512 + j0 + jj) * bstride + kbase + csrc * 8, &Bs[e * 8]);
    }
    __syncthreads();
#pragma unroll
    for (int kk = 0; kk < 512; kk += 32) {
      int cA = (kk >> 3) + lg;          // 16B chunk index of this quarter-wave
      int cx = (cA ^ (lr & 7)) * 8;     // swizzled elem offset
      bf16x8 bf = *(const bf16x8*)&Bs[(g * 16 + lr) * 512 + cx];
      bf16x8 a0 = *(const bf16x8*)&As[(mh + lr) * 512 + cx];
      bf16x8 a1 = *(const bf16x8*)&As[(mh + 16 + lr) * 512 + cx];
      acc[0] = __builtin_amdgcn_mfma_f32_16x16x32_bf16(a0, bf, acc[0], 0, 0, 0);
      acc[1] = __builtin_amdgcn_mfma_f32_16x16x32_bf16(a1, bf, acc[1], 0, 0, 0);
    }
    if (pass + 1 < npass) __syncthreads();
  }

  // add Xpre (L1) / bias (L2); publish gates. C/D layout: col=lane&15, row=(lane>>4)*4+q
#pragma unroll
  for (int i = 0; i < 2; ++i) {
#pragma unroll
    for (int q = 0; q < 4; ++q) {
      int rl = mh + i * 16 + lg * 4 + q;   // local batch row
      float add = isL2 ? b2[g * 512 + j0 + lr]
                       : bf2f(Xpre[(size_t)(m0 + rl) * NG_ + g * 512 + j0 + lr]);
      Gs[g][rl][lr] = acc[i][q] + add;
    }
  }
  __syncthreads();
  // cell update: 64x16 = 1024 cells / 512 threads
  float* cst = isL2 ? c2 : c1;
  const int off = isL2 ? 512 : 0;
#pragma unroll
  for (int u = 0; u < 2; ++u) {
    int cell = u * 512 + tid;
    int bl = cell >> 4, jl = cell & 15;
    float gi = Gs[0][bl][jl], gf = Gs[1][bl][jl], gm = Gs[2][bl][jl], go = Gs[3][bl][jl];
    float iv = 1.f / (1.f + expf(-gi));
    float fv = 1.f / (1.f + expf(-gf));
    float mv = tanhf(gm);
    float ov = 1.f / (1.f + expf(-go));
    int idx = (m0 + bl) * HID_ + j0 + jl;
    float cn = mv * iv + fv * cst[idx];
    cst[idx] = cn;
    Aout[(size_t)(m0 + bl) * 1024 + off + j0 + jl] = f2bf(ov * tanhf(cn));
  }
}

// ---------------- output projection from Acat: h2(t) = SLOT(t+1)[:,512:] ----------------
__global__ __launch_bounds__(320) void out_proj(const u16* __restrict__ Acat,
                                                const float* __restrict__ Wo,
                                                const float* __restrict__ bo,
                                                float* __restrict__ out) {
  __shared__ __align__(16) u16 Hs[32 * 520];  // +8 pad kills bank conflicts
  const int r0 = blockIdx.x * 32;             // flat row = t*256 + b
  const int tid = threadIdx.x;
  for (int e = tid; e < 2048; e += 320) {
    int rl = e >> 6, k8 = (e & 63) * 8;
    int r = r0 + rl, t = r >> 8, b = r & 255;
    *(uint4*)&Hs[rl * 520 + k8] =
        *(const uint4*)(Acat + (size_t)(t + 2) * (BATCH_ * 1024) + (size_t)b * 1024 + 512 + k8);
  }
  __syncthreads();
  if (tid < 288) {
    int rl = tid / 9, cls = tid - rl * 9;
    const u16* h = &Hs[rl * 520];
    const float* wv = Wo + cls * HID_;
    float s = bo[cls];
#pragma unroll 8
    for (int k = 0; k < HID_; ++k) s += bf2f(h[k]) * wv[k];
    int r = r0 + rl, t = r >> 8, b = r & 255;
    out[((size_t)b * SEQ_ + t) * NCLS_ + cls] = s;
  }
}

extern "C" void kernel_launch(void* const* d_in, const int* in_sizes, int n_in,
                              void* d_out, int out_size, void* d_ws, size_t ws_size,
                              hipStream_t stream) {
  (void)in_sizes; (void)n_in; (void)out_size; (void)ws_size;
  const int*   ids = (const int*)d_in[0];
  const float* tok = (const float*)d_in[1];
  const float* pos = (const float*)d_in[2];
  const float* W1  = (const float*)d_in[3];
  const float* R1  = (const float*)d_in[4];
  const float* b1  = (const float*)d_in[5];
  const float* W2  = (const float*)d_in[6];
  const float* R2  = (const float*)d_in[7];
  const float* b2  = (const float*)d_in[8];
  const float* Wo  = (const float*)d_in[9];
  const float* bo  = (const float*)d_in[10];
  float* out = (float*)d_out;

  // workspace layout (~212 MB); Acat overlays Xbf (dead after phase A)
  char* p = (char*)d_ws;
  auto alloc = [&](size_t bytes) { char* q = p; p += (bytes + 255) & ~(size_t)255; return q; };
  u16*  W1b  = (u16*)alloc((size_t)NG_ * DIN_ * 2);
  u16*  R1b  = (u16*)alloc((size_t)NG_ * HID_ * 2);
  u16*  W2c  = (u16*)alloc((size_t)NG_ * 1024 * 2);               // [W2|R2]
  float* c1  = (float*)alloc((size_t)BATCH_ * HID_ * 4);
  float* c2  = (float*)alloc((size_t)BATCH_ * HID_ * 4);
  size_t xbf_bytes  = (size_t)SEQ_ * BATCH_ * DIN_ * 2;           // 50.3 MB
  size_t acat_bytes = (size_t)(SEQ_ + 2) * BATCH_ * 1024 * 2;     // 68.2 MB
  u16*  Xbf  = (u16*)alloc(acat_bytes > xbf_bytes ? acat_bytes : xbf_bytes);
  u16*  Acat = Xbf;                                               // overlay
  u16*  Xpre = (u16*)alloc((size_t)SEQ_ * BATCH_ * NG_ * 2);      // 134 MB

  // SLOT(t) = Acat + (t+1)*BATCH_*1024
  auto SLOT = [&](int t) { return Acat + (size_t)(t + 1) * BATCH_ * 1024; };

  // zero cell states (adjacent allocs -> one memset)
  hipMemsetAsync(c1, 0, (size_t)BATCH_ * HID_ * 4 * 2, stream);

  // weight casts
  castk<<<dim3((NG_ * DIN_ / 4 + 255) / 256), 256, 0, stream>>>(W1, W1b, NG_ * DIN_ / 4);
  castk<<<dim3((NG_ * HID_ / 4 + 255) / 256), 256, 0, stream>>>(R1, R1b, NG_ * HID_ / 4);
  cast2<<<dim3(1024), 256, 0, stream>>>(W2, W2c, 0);
  cast2<<<dim3(1024), 256, 0, stream>>>(R2, W2c, 512);

  // embeds -> (S,B,768) bf16
  embed_k<<<dim3(SEQ_ * BATCH_), 192, 0, stream>>>(ids, tok, pos, Xbf);

  // phase A: X1pre = X @ W1^T + b1   (32768 x 2048, K=768)
  gemm_bt<<<dim3(NG_ / 128, SEQ_ * BATCH_ / 128), 256, 0, stream>>>(
      Xbf, W1b, b1, Xpre, SEQ_ * BATCH_, NG_, DIN_);

  // Xbf now dead; zero SLOT(-1) and SLOT(0) (h1(-1)=0, h2(-1)=0)
  hipMemsetAsync(Acat, 0, (size_t)2 * BATCH_ * 1024 * 2, stream);

  // wavefront recurrence: launch k does L1(t=k) and L2(t=k-1)
  for (int k = 0; k <= SEQ_; ++k) {
    int nL1 = (k < SEQ_) ? 128 : 0;
    int nL2 = (k > 0) ? 128 : 0;
    int kx = k < SEQ_ ? k : SEQ_ - 1;
    lstm_step<<<dim3(nL1 + nL2), 512, 0, stream>>>(
        SLOT(k - 1), SLOT(k), Xpre + (size_t)kx * BATCH_ * NG_,
        R1b, W2c, b2, c1, c2, nL1);
  }

  // logits
  out_proj<<<dim3(SEQ_ * BATCH_ / 32), 320, 0, stream>>>(Acat, Wo, bo, out);
}